// Round 5
// baseline (1301.511 us; speedup 1.0000x reference)
//
#include <hip/hip_runtime.h>

// ---------------------------------------------------------------------------
// LSTM layer, T=512 B=64 D=H=1024, out = h_T (64x1024 fp32).
// Round 10: r9 (1062us, known-good) + ONE change: low-traffic polling.
//   KEPT (load-bearing): syncA+syncB skeleton, 8 coarse flags/group at 128B,
//     one tid0 add per block/step, fragment-major hq + lane-linear gather,
//     gl XOR-swizzle, x-DMA before poll.
//   CHANGED: poll concentration. r9 had every lane of every wave polling the
//     global flags: 256 blocks x 512 lanes hammering 32 cache lines with
//     coherent loads every ~800cy (~330K L3 accesses/step) - the producers'
//     flag RMWs queue behind this firehose, inflating the very latency the
//     poll waits on. Now: wave 0 lanes 0-7 poll the 8 flags (one 8-lane
//     vector load per iteration, ~64x less traffic); lane 0 then publishes a
//     monotonic LDS sentinel s_ready = t+1; waves 1-7 spin on LDS (free).
//   Ordering: producer h-stores drained (syncB vmcnt0) before flag add;
//     wave0 sees flags -> LDS write; LDS block-coherent; gathers are
//     control-dependent + sc0 sc1 -> fetch from coherence point. Unchanged
//     protocol arithmetic: flag = 8*(t+1) after step-t publishes.
// ---------------------------------------------------------------------------

typedef __attribute__((ext_vector_type(8))) short     short8;   // 8 bf16 (4 VGPR)
typedef __attribute__((ext_vector_type(4))) float     f32x4;
typedef __attribute__((ext_vector_type(8))) unsigned short ushort8v;
typedef __attribute__((ext_vector_type(4))) unsigned short ushort4v;
typedef __attribute__((ext_vector_type(4))) unsigned int   uint4v;

__device__ __forceinline__ unsigned short f2bf(float f) {
  unsigned int u = __float_as_uint(f);
  u += 0x7FFFu + ((u >> 16) & 1u);          // RNE
  return (unsigned short)(u >> 16);
}

__device__ __forceinline__ void dma16(const void* g, void* l) {
  __builtin_amdgcn_global_load_lds(
      (const __attribute__((address_space(1))) unsigned int*)g,
      (__attribute__((address_space(3))) unsigned int*)l, 16, 0, 0);
}

__device__ __forceinline__ float sig2(float x) {   // = (tanh(x)+1)/2 = sigma(2x)
  return __builtin_amdgcn_rcpf(1.f + __expf(-2.f * x));
}

// ---------------- prep 1: cast x -> bf16; zero flags ------------------------
__global__ void k_cast_x(const float* __restrict__ x, unsigned short* __restrict__ xb,
                         int* __restrict__ flags) {
  long i = ((long)blockIdx.x * 256 + threadIdx.x) * 8;
  f32x4 a = *(const f32x4*)(x + i);
  f32x4 b = *(const f32x4*)(x + i + 4);
  ushort8v o;
  o[0] = f2bf(a[0]); o[1] = f2bf(a[1]); o[2] = f2bf(a[2]); o[3] = f2bf(a[3]);
  o[4] = f2bf(b[0]); o[5] = f2bf(b[1]); o[6] = f2bf(b[2]); o[7] = f2bf(b[3]);
  *(ushort8v*)(xb + i) = o;
  if (blockIdx.x < 4) flags[(blockIdx.x << 8) + threadIdx.x] = 0;   // 1024 ints
}

// ---------------- prep 2: transpose-cast 8 x (1024x1024 fp32 -> [n][k] bf16)
__global__ void k_tcast8(const float* __restrict__ s0, const float* __restrict__ s1,
                         const float* __restrict__ s2, const float* __restrict__ s3,
                         const float* __restrict__ s4, const float* __restrict__ s5,
                         const float* __restrict__ s6, const float* __restrict__ s7,
                         unsigned short* __restrict__ dstBase) {
  __shared__ unsigned short tile[64][65];
  const int z = blockIdx.z;
  const float* src = (z == 0) ? s0 : (z == 1) ? s1 : (z == 2) ? s2 : (z == 3) ? s3
                   : (z == 4) ? s4 : (z == 5) ? s5 : (z == 6) ? s6 : s7;
  unsigned short* dst = dstBase + (size_t)z * 1048576;
  const int k0 = blockIdx.x << 6;
  const int n0 = blockIdx.y << 6;
  const int tid = threadIdx.x;
#pragma unroll
  for (int i = 0; i < 4; ++i) {
    int q = tid + (i << 8);
    int r = q >> 4, c4 = (q & 15) << 2;
    f32x4 v = *(const f32x4*)(src + (size_t)(k0 + r) * 1024 + n0 + c4);
    tile[r][c4 + 0] = f2bf(v[0]);
    tile[r][c4 + 1] = f2bf(v[1]);
    tile[r][c4 + 2] = f2bf(v[2]);
    tile[r][c4 + 3] = f2bf(v[3]);
  }
  __syncthreads();
#pragma unroll
  for (int i = 0; i < 4; ++i) {
    int q = tid + (i << 8);
    int rn = q >> 4, kc = (q & 15) << 2;
    ushort4v o;
    o[0] = tile[kc + 0][rn];
    o[1] = tile[kc + 1][rn];
    o[2] = tile[kc + 2][rn];
    o[3] = tile[kc + 3][rn];
    *(ushort4v*)(dst + (size_t)(n0 + rn) * 1024 + k0 + kc) = o;
  }
}

// coherent gather of 4 A-fragments; addresses are lane-linear (ln*16B) per
// chunk. Final vmcnt(0) also drains this wave's x-DMA (wave-private Xs).
#define GATHER_WAIT(F0, F1, F2, F3, P0, P1, P2, P3)                      \
  asm volatile(                                                          \
      "global_load_dwordx4 %0, %4, off sc0 sc1\n\t"                      \
      "global_load_dwordx4 %1, %5, off sc0 sc1\n\t"                      \
      "global_load_dwordx4 %2, %6, off sc0 sc1\n\t"                      \
      "global_load_dwordx4 %3, %7, off sc0 sc1\n\t"                      \
      "s_waitcnt vmcnt(0)"                                               \
      : "=&v"(F0), "=&v"(F1), "=&v"(F2), "=&v"(F3)                       \
      : "v"(P0), "v"(P1), "v"(P2), "v"(P3)                               \
      : "memory")

// ---------------- main: persistent recurrence -------------------------------
__global__ __launch_bounds__(512, 2) void k_lstm(
    const unsigned short* __restrict__ xb,    // [512*64][1024] bf16
    const unsigned short* __restrict__ WtT,   // [4096][1024] bf16, n = gate*1024+u
    const unsigned short* __restrict__ RtT,
    const float* __restrict__ b_i, const float* __restrict__ b_f,
    const float* __restrict__ b_o, const float* __restrict__ b_c,
    const float* __restrict__ s0, const float* __restrict__ c0,
    unsigned int* __restrict__ hq,            // [4 bg][2 buf][32 K][64 lane][4] dw
    int* __restrict__ flags, float* __restrict__ out) {
  __shared__ __align__(16) unsigned short Xs[2][16384];   // 2 x 32 KB
  __shared__ __align__(16) float gl[8192];                // 32 KB (96 KB total)
  __shared__ int s_ready;                                 // monotonic step sentinel

  const int tid = threadIdx.x;
  const int bid = blockIdx.x;                 // 256 blocks = 4 bg x 64 cs
  const int cs = bid & 63;
  const int bg = bid >> 6;
  const int u0 = cs << 4;                     // 16 units
  const int b0 = bg << 4;                     // 16 batch rows
  const int wv = tid >> 6, ln = tid & 63;
  const int qd = ln >> 4, nc = ln & 15;
  const int grow = ln >> 2;                   // 0..15 (row for x-DMA)
  const int gsub = ln & 3;                    // 0..3  (global octet)
  const int gsx = gsub ^ (grow & 3);          // swizzled octet (Xs layout)

  // ---- weights: wave wv owns chunks K = j4*8 + wv, ALL 4 gates ----
  short8 wfr[4][4], rfr[4][4];
#pragma unroll
  for (int j4 = 0; j4 < 4; ++j4) {
    const int K = (j4 << 3) + wv;
#pragma unroll
    for (int g = 0; g < 4; ++g) {
      const size_t off = ((size_t)((g << 10) + u0 + nc) << 10) + (K << 5) + (qd << 3);
      wfr[j4][g] = *(const short8*)(WtT + off);
      rfr[j4][g] = *(const short8*)(RtT + off);
    }
  }

  // ---- per-thread state (tid<256): cell (m, un) ----
  const int m = tid >> 4, un = tid & 15;
  const int gio = (b0 + m) * 1024 + u0 + un;
  float c = 0.f, bi = 0.f, bff = 0.f, bo = 0.f, bc = 0.f;
  const int hq_bg = bg << 14;                 // dword base of this group's region
  // fragment-major producer slot: K=cs>>1, qd'=((cs&1)<<1)|(un>>3),
  // lane'=qd'*16+m, d=(un>>1)&3  (only even-un threads store)
  const int hw0 = hq_bg + ((cs >> 1) << 8) +
                  (((((cs & 1) << 1) | (un >> 3)) << 4) + m) * 4 + ((un >> 1) & 3);
  if (tid == 0) s_ready = 0;
  if (tid < 256) {
    c = c0[gio];
    bi = b_i[u0 + un]; bff = b_f[u0 + un]; bo = b_o[u0 + un]; bc = b_c[u0 + un];
    float h0 = s0[gio];
    float hp = __shfl_xor(h0, 1);
    if (!(tid & 1)) {                         // publish h_0 into buf 0
      unsigned int wd = (unsigned int)f2bf(h0) | ((unsigned int)f2bf(hp) << 16);
      __hip_atomic_store(&hq[hw0], wd, __ATOMIC_RELAXED, __HIP_MEMORY_SCOPE_AGENT);
    }
  }
  // ---- stage x_0 (wave-private chunks; lds base is wave-uniform) ----
#pragma unroll
  for (int j4 = 0; j4 < 4; ++j4) {
    const int K = (j4 << 3) + wv;
    dma16(xb + (((size_t)(b0 + grow)) << 10) + (K << 5) + (gsx << 3), &Xs[0][K << 9]);
  }
  __syncthreads();                            // drains h0 stores + x0 DMA; s_ready=0
  if (tid == 0)
    __hip_atomic_fetch_add(&flags[((bg << 3) + (bid & 7)) << 5], 1,
                           __ATOMIC_RELAXED, __HIP_MEMORY_SCOPE_AGENT);

  // consumer gather bases: lane-linear. chunk K=wv+8*j4 at +j4*2048 dwords
  const unsigned int* const pbE = hq + hq_bg + (wv << 8) + (ln << 2);
  const unsigned int* const pbO = pbE + 8192;
  // wave-0 poll address (lanes 0-7 only)
  int* const pollp = &flags[((bg << 3) + (ln & 7)) << 5];
  // gl swizzled read base (matches writer's rr^qd swizzle)
  const int rbase = (tid & 0xC0) + ((((tid >> 4) ^ (tid >> 6)) & 3) << 4) + (tid & 15);

  for (int t = 0; t < 512; ++t) {
    f32x4 acc[4] = {{0.f,0.f,0.f,0.f},{0.f,0.f,0.f,0.f},{0.f,0.f,0.f,0.f},{0.f,0.f,0.f,0.f}};
    // ---- x half (wave-private chunks) ----
    {
      const unsigned short* xsb = &Xs[t & 1][0];
#pragma unroll
      for (int j4 = 0; j4 < 4; ++j4) {
        const int K = (j4 << 3) + wv;
        short8 a = *(const short8*)(xsb + (K << 9) + (nc << 5) + ((qd ^ (nc & 3)) << 3));
#pragma unroll
        for (int g = 0; g < 4; ++g)
          acc[g] = __builtin_amdgcn_mfma_f32_16x16x32_bf16(a, wfr[j4][g], acc[g], 0, 0, 0);
      }
    }
    // ---- issue x_{t+1} DMA: drains during the poll, off the signal path ----
    {
      const int tn = (t + 1) & 511;
      const size_t xrow = (size_t)((tn << 6) + b0 + grow) << 10;
      unsigned short* xd = &Xs[(t + 1) & 1][0];
#pragma unroll
      for (int j4 = 0; j4 < 4; ++j4) {
        const int K = (j4 << 3) + wv;
        dma16(xb + xrow + (K << 5) + (gsx << 3), xd + (K << 9));
      }
    }
    // ---- poll: wave 0 lanes 0-7 watch the 8 flags; waves 1-7 spin on LDS ----
    {
      const int target = (t + 1) << 3;
      if (wv == 0) {
        int v = target;                       // lanes 8-63 auto-pass
        for (;;) {
          if (ln < 8)
            v = __hip_atomic_load(pollp, __ATOMIC_RELAXED, __HIP_MEMORY_SCOPE_AGENT);
          if (__all(v >= target)) break;
          __builtin_amdgcn_s_sleep(1);
        }
        if (ln == 0)
          __hip_atomic_store(&s_ready, t + 1, __ATOMIC_RELAXED,
                             __HIP_MEMORY_SCOPE_WORKGROUP);
      } else {
        while (__hip_atomic_load(&s_ready, __ATOMIC_RELAXED,
                                 __HIP_MEMORY_SCOPE_WORKGROUP) < t + 1)
          __builtin_amdgcn_s_sleep(1);
      }
    }
    // ---- gather h_t directly as A-fragments (lane-linear, coherent) ----
    const unsigned int* pb = (t & 1) ? pbO : pbE;
    uint4v f0, f1, f2, f3;
    GATHER_WAIT(f0, f1, f2, f3, pb, pb + 2048, pb + 4096, pb + 6144);
    // ---- h half (no Hs bounce) ----
    {
      short8 a0 = __builtin_bit_cast(short8, f0);
      short8 a1 = __builtin_bit_cast(short8, f1);
      short8 a2 = __builtin_bit_cast(short8, f2);
      short8 a3 = __builtin_bit_cast(short8, f3);
#pragma unroll
      for (int g = 0; g < 4; ++g) {
        acc[g] = __builtin_amdgcn_mfma_f32_16x16x32_bf16(a0, rfr[0][g], acc[g], 0, 0, 0);
        acc[g] = __builtin_amdgcn_mfma_f32_16x16x32_bf16(a1, rfr[1][g], acc[g], 0, 0, 0);
        acc[g] = __builtin_amdgcn_mfma_f32_16x16x32_bf16(a2, rfr[2][g], acc[g], 0, 0, 0);
        acc[g] = __builtin_amdgcn_mfma_f32_16x16x32_bf16(a3, rfr[3][g], acc[g], 0, 0, 0);
      }
      float* glw = &gl[wv << 10];
#pragma unroll
      for (int g = 0; g < 4; ++g)
#pragma unroll
        for (int rr = 0; rr < 4; ++rr)
          glw[(g << 8) + (qd << 6) + (((rr ^ qd) & 3) << 4) + nc] = acc[g][rr];
    }
    __syncthreads();                          // gl ready (syncA)
    // ---- gates, state update, publish h_{t+1} ----
    if (tid < 256) {
      float pi = bi, pfv = bff, po = bo, pc = bc;
      const float* glb = &gl[rbase];
#pragma unroll
      for (int w = 0; w < 8; ++w) {
        const float* glr = glb + (w << 10);
        pi += glr[0]; pfv += glr[256]; po += glr[512]; pc += glr[768];
      }
      float it = sig2(pi), ft = sig2(pfv), ot = sig2(po);
      float ch = 2.f * sig2(pc) - 1.f;
      c = ft * c + it * ch;
      float h = ot * (2.f * sig2(c) - 1.f);
      if (t < 511) {
        float hp = __shfl_xor(h, 1);
        if (!(tid & 1)) {
          unsigned int wd = (unsigned int)f2bf(h) | ((unsigned int)f2bf(hp) << 16);
          __hip_atomic_store(&hq[hw0 + (((t + 1) & 1) << 13)], wd,
                             __ATOMIC_RELAXED, __HIP_MEMORY_SCOPE_AGENT);
        }
      } else {
        out[gio] = h;
      }
    }
    __syncthreads();                          // h stores drained (syncB)
    if (tid == 0)
      __hip_atomic_fetch_add(&flags[((bg << 3) + (bid & 7)) << 5], 1,
                             __ATOMIC_RELAXED, __HIP_MEMORY_SCOPE_AGENT);
  }
}

// ---------------------------------------------------------------------------
extern "C" void kernel_launch(void* const* d_in, const int* in_sizes, int n_in,
                              void* d_out, int out_size, void* d_ws, size_t ws_size,
                              hipStream_t stream) {
  const float* x   = (const float*)d_in[0];
  const float* W_i = (const float*)d_in[1];
  const float* W_f = (const float*)d_in[2];
  const float* W_c = (const float*)d_in[3];
  const float* W_o = (const float*)d_in[4];
  const float* R_i = (const float*)d_in[5];
  const float* R_f = (const float*)d_in[6];
  const float* R_c = (const float*)d_in[7];
  const float* R_o = (const float*)d_in[8];
  const float* b_i = (const float*)d_in[9];
  const float* b_f = (const float*)d_in[10];
  const float* b_c = (const float*)d_in[11];
  const float* b_o = (const float*)d_in[12];
  const float* s0  = (const float*)d_in[13];
  const float* c0  = (const float*)d_in[14];
  float* out = (float*)d_out;

  char* ws = (char*)d_ws;
  unsigned short* xb  = (unsigned short*)(ws);                               // 64 MB
  unsigned short* WtT = (unsigned short*)(ws + (size_t)67108864);            // 8 MB
  unsigned short* RtT = (unsigned short*)(ws + (size_t)67108864 + 8388608);  // 8 MB
  unsigned int*   hq  = (unsigned int*)(ws + (size_t)67108864 + 16777216);   // 256 KB
  int* flags          = (int*)(ws + (size_t)67108864 + 16777216 + 262144);   // 4 KB

  k_cast_x<<<16384, 256, 0, stream>>>(x, xb, flags);
  // gate order i,f,o,c; z 0..3 -> W into WtT, z 4..7 -> R into RtT (contiguous)
  dim3 tg(16, 16, 8);
  k_tcast8<<<tg, 256, 0, stream>>>(W_i, W_f, W_o, W_c, R_i, R_f, R_o, R_c, WtT);

  k_lstm<<<256, 512, 0, stream>>>(xb, WtT, RtT, b_i, b_f, b_o, b_c, s0, c0,
                                  hq, flags, out);
}